// Round 7
// baseline (139.488 us; speedup 1.0000x reference)
//
#include <hip/hip_runtime.h>
#include <math.h>
#include <stdint.h>

typedef __attribute__((ext_vector_type(8))) short bf16x8;
typedef __attribute__((ext_vector_type(4))) float f32x4;
typedef __attribute__((ext_vector_type(4))) int   i32x4;
typedef __attribute__((ext_vector_type(2))) int   i32x2;

#define NSITES 128
#define NBULK  126
#define BOND   64
#define BATCH  8192

#define WSITE     49152                             // 2v*3tm*2ks*4jt*1024B per site
#define WMASK_OFF ((size_t)NBULK * (size_t)WSITE)   // 6193152
#define WS_NEED   (WMASK_OFF + (size_t)BATCH * 16)

// LDS: single env buffer per cohort (c0 @0, c1 @6144) + reduce scratch
#define RED_OFF 12288
#define SMEM_SZ 12800

#define MFMA_BF16 __builtin_amdgcn_mfma_f32_16x16x32_bf16

// ============ prepass 1: split bulk into 3 trunc-bf16 planes, fragment-linear image ====
__global__ void prep_w(const float* __restrict__ bulk, char* __restrict__ wsd) {
    const int s  = blockIdx.x;
    const int t  = threadIdx.x;          // 256
    const int jt = (t >> 6) & 3;
    const int l  = t & 63;
    const int j  = jt * 16 + (l & 15);
    const int kb0 = (l >> 4) * 8;
    const float* bs = bulk + (size_t)s * 8192;
    char* dsite = wsd + (size_t)s * WSITE;
    #pragma unroll
    for (int ks = 0; ks < 2; ++ks) {
        const int kb = ks * 32 + kb0;
        #pragma unroll
        for (int v = 0; v < 2; ++v) {
            uint h[3][8];
            #pragma unroll
            for (int e = 0; e < 8; ++e) {
                const float x = bs[(size_t)(kb + e) * 128 + v * 64 + j];
                const uint  u1 = __float_as_uint(x) & 0xffff0000u;
                const float r1 = x - __uint_as_float(u1);
                const uint  u2 = __float_as_uint(r1) & 0xffff0000u;
                const float r2 = r1 - __uint_as_float(u2);
                h[0][e] = u1; h[1][e] = u2;
                h[2][e] = __float_as_uint(r2) & 0xffff0000u;
            }
            #pragma unroll
            for (int tm = 0; tm < 3; ++tm) {
                i32x4 q;
                q.x = (int)((h[tm][0] >> 16) | (h[tm][1] & 0xffff0000u));
                q.y = (int)((h[tm][2] >> 16) | (h[tm][3] & 0xffff0000u));
                q.z = (int)((h[tm][4] >> 16) | (h[tm][5] & 0xffff0000u));
                q.w = (int)((h[tm][6] >> 16) | (h[tm][7] & 0xffff0000u));
                *(i32x4*)(dsite + ((((v*3+tm)*2+ks)*4 + jt) * 1024) + l * 16) = q;
            }
        }
    }
}

// ============ prepass 2: pack per-batch v bits into 4 uints via ballot ============
__global__ void prep_mask(const int* __restrict__ cfg, uint* __restrict__ msk) {
    const int w = threadIdx.x >> 6, l = threadIdx.x & 63;   // 256 thr = 4 waves
    const int b = blockIdx.x * 2 + (w >> 1);
    const int half = w & 1;
    int idx = half * 64 + l + 1;
    if (idx > 127) idx = 127;
    const int v = cfg[b * NSITES + idx];
    const unsigned long long bal = __ballot(v != 0);
    if (l == 0) {
        msk[b * 4 + half * 2]     = (uint)(bal & 0xffffffffu);
        msk[b * 4 + half * 2 + 1] = (uint)(bal >> 32);
    }
}

// ============ main kernel: 4 waves, 32 rows, phase-split cohorts, raw barriers ======

#define LOADA_(P,V,T,K) \
    asm volatile("global_load_dwordx4 %0, %1, off" \
                 : "=v"(A_##P##_##V##T##K) \
                 : "v"(gp_ + aG[V][T][K]) : "memory")
#define LOADA(P,V,T,K) LOADA_(P,V,T,K)

#define PREFETCH(S, P) do { \
    const char* gp_ = ws + (size_t)(((S) < NBULK) ? (S) : 0) * WSITE; \
    LOADA(P,0,0,0); LOADA(P,0,0,1); LOADA(P,0,1,0); LOADA(P,0,1,1); \
    LOADA(P,0,2,0); LOADA(P,0,2,1); LOADA(P,1,0,0); LOADA(P,1,0,1); \
    LOADA(P,1,1,0); LOADA(P,1,1,1); LOADA(P,1,2,0); LOADA(P,1,2,1); \
} while (0)

#define AF_(P,V,T,K) (__builtin_bit_cast(bf16x8, A_##P##_##V##T##K))
#define AF(P,V,T,K) AF_(P,V,T,K)

// select + optional scale/max + 3-term split + env publish (ds_write)
#define EPI(EG, A0, A1, BIT, DOSC, DOMX, ROFF, LS, WB) do { \
    const bool vv_ = (BIT) != 0u; \
    EG.x = vv_ ? A1.x : A0.x; EG.y = vv_ ? A1.y : A0.y; \
    EG.z = vv_ ? A1.z : A0.z; EG.w = vv_ ? A1.w : A0.w; \
    if (DOSC) { \
        f32x4 m4_ = *(const f32x4*)(smem + (ROFF) + lb * 16); \
        const float mm_ = fmaxf(fmaxf(m4_.x, m4_.y), fmaxf(m4_.z, m4_.w)); \
        const int ee_ = (__float_as_int(mm_) >> 23) & 255; \
        const float sc_ = __int_as_float((254 - ee_) << 23); \
        LS += (float)(ee_ - 127) * 0.6931471805599453f; \
        EG.x *= sc_; EG.y *= sc_; EG.z *= sc_; EG.w *= sc_; \
    } \
    if (DOMX) { \
        float mm_ = fmaxf(fmaxf(fabsf(EG.x), fabsf(EG.y)), fmaxf(fabsf(EG.z), fabsf(EG.w))); \
        mm_ = fmaxf(mm_, __shfl_xor(mm_, 16)); mm_ = fmaxf(mm_, __shfl_xor(mm_, 32)); \
        if (lg == 0) *(float*)(smem + (ROFF) + lb * 16 + jt * 4) = mm_; \
    } \
    uint p1_[4], p2_[4], p3_[4]; \
    const float ev_[4] = {EG.x, EG.y, EG.z, EG.w}; \
    _Pragma("unroll") \
    for (int r = 0; r < 4; ++r) { \
        const float x_ = ev_[r]; \
        const uint  u1_ = __float_as_uint(x_) & 0xffff0000u; \
        const float r1_ = x_ - __uint_as_float(u1_); \
        const uint  u2_ = __float_as_uint(r1_) & 0xffff0000u; \
        const float r2_ = r1_ - __uint_as_float(u2_); \
        p1_[r] = u1_; p2_[r] = u2_; \
        p3_[r] = __float_as_uint(r2_) & 0xffff0000u; \
    } \
    { i32x2 d_; d_.x = (int)((p1_[0] >> 16) | (p1_[1] & 0xffff0000u)); \
      d_.y = (int)((p1_[2] >> 16) | (p1_[3] & 0xffff0000u)); \
      *(i32x2*)(smem + (WB) + aWr) = d_; } \
    { i32x2 d_; d_.x = (int)((p2_[0] >> 16) | (p2_[1] & 0xffff0000u)); \
      d_.y = (int)((p2_[2] >> 16) | (p2_[3] & 0xffff0000u)); \
      *(i32x2*)(smem + (WB) + aWr + 2048) = d_; } \
    { i32x2 d_; d_.x = (int)((p3_[0] >> 16) | (p3_[1] & 0xffff0000u)); \
      d_.y = (int)((p3_[2] >> 16) | (p3_[3] & 0xffff0000u)); \
      *(i32x2*)(smem + (WB) + aWr + 4096) = d_; } \
} while (0)

// 24 MFMAs for one cohort, 4 independent chains (plane x ks), summed at the end
#define MS4(P, TW, TE, BF) \
    q00_ = MFMA_BF16(AF(P,0,TW,0), BF[TE][0], q00_, 0, 0, 0); \
    q10_ = MFMA_BF16(AF(P,1,TW,0), BF[TE][0], q10_, 0, 0, 0); \
    q01_ = MFMA_BF16(AF(P,0,TW,1), BF[TE][1], q01_, 0, 0, 0); \
    q11_ = MFMA_BF16(AF(P,1,TW,1), BF[TE][1], q11_, 0, 0, 0);

#define MFMA24(A0, A1, P, BF) do { \
    f32x4 q00_ = {0.f,0.f,0.f,0.f}, q01_ = {0.f,0.f,0.f,0.f}; \
    f32x4 q10_ = {0.f,0.f,0.f,0.f}, q11_ = {0.f,0.f,0.f,0.f}; \
    MS4(P,2,0,BF) MS4(P,1,1,BF) MS4(P,0,2,BF) \
    MS4(P,1,0,BF) MS4(P,0,1,BF) MS4(P,0,0,BF) \
    A0 = q00_ + q01_;  A1 = q10_ + q11_; \
} while (0)

// Phase A: read env_c0, prefetch A[s+1], epi_c1 (VALU) interleaved with MFMA c0
#define PHASE_A(S, P, NP, BIT1, SC1, MX1) do { \
    bf16x8 Bf_[3][2]; \
    _Pragma("unroll") \
    for (int tm = 0; tm < 3; ++tm) { \
        Bf_[tm][0] = *(const bf16x8*)(smem + aB0 + tm * 2048); \
        Bf_[tm][1] = *(const bf16x8*)(smem + aB1 + tm * 2048); \
    } \
    PREFETCH((S) + 1, NP); \
    asm volatile("s_waitcnt vmcnt(12)" ::: "memory"); \
    __builtin_amdgcn_sched_barrier(0); \
    EPI(eg1, acC1_0, acC1_1, BIT1, SC1, MX1, RED_OFF + 256, ls1, 6144); \
    MFMA24(acC0_0, acC0_1, P, Bf_); \
    asm volatile("s_waitcnt lgkmcnt(0)" ::: "memory"); \
    __builtin_amdgcn_s_barrier(); \
} while (0)

// Phase B: read env_c1, epi_c0 interleaved with MFMA c1
#define PHASE_B(S, P, BIT0, SC0, MX0) do { \
    bf16x8 Bf_[3][2]; \
    _Pragma("unroll") \
    for (int tm = 0; tm < 3; ++tm) { \
        Bf_[tm][0] = *(const bf16x8*)(smem + 6144 + aB0 + tm * 2048); \
        Bf_[tm][1] = *(const bf16x8*)(smem + 6144 + aB1 + tm * 2048); \
    } \
    EPI(eg0, acC0_0, acC0_1, BIT0, SC0, MX0, RED_OFF, ls0, 0); \
    MFMA24(acC1_0, acC1_1, P, Bf_); \
    asm volatile("s_waitcnt lgkmcnt(0)" ::: "memory"); \
    __builtin_amdgcn_s_barrier(); \
} while (0)

#define SITEPAIR(S, I2, M0, M1S, CSC, CMX) do { \
    PHASE_A((S),     0, 1, ((M1S) >> (I2)) & 1u,        false,               false); \
    PHASE_B((S),     0,    ((M0)  >> (I2)) & 1u,        (CSC) && (I2) == 0,  (CMX) && (I2) == 30); \
    PHASE_A((S) + 1, 1, 0, ((M1S) >> ((I2)+1)) & 1u,    (CSC) && (I2) == 0,  (CMX) && (I2) == 30); \
    PHASE_B((S) + 1, 1,    ((M0)  >> ((I2)+1)) & 1u,    false,               false); \
} while (0)

#define RUN_CHUNK(CB, M0, M1S, CNT, CSC, CMX) { \
    _Pragma("unroll 1") \
    for (int i2 = 0; i2 < (CNT); i2 += 2) \
        SITEPAIR((CB) * 32 + i2, i2, M0, M1S, CSC, CMX); \
}

__global__ __launch_bounds__(256, 1) void mps_main(
    const int*   __restrict__ cfg,
    const float* __restrict__ left,
    const float* __restrict__ right,
    const char*  __restrict__ ws,
    float*       __restrict__ out)
{
    extern __shared__ __align__(16) char smem[];
    const int t  = threadIdx.x;
    const int w  = t >> 6, l = t & 63;
    const int lg = l >> 4, lb = l & 15;
    const int jt = w;                       // 4 waves = 4 j-tiles
    const int bbase = blockIdx.x * 32;
    const int b0 = bbase + lb, b1 = bbase + 16 + lb;

    // per-lane global fragment offsets within a site image
    int aG[2][3][2];
    #pragma unroll
    for (int vv = 0; vv < 2; ++vv)
        #pragma unroll
        for (int tm = 0; tm < 3; ++tm)
            #pragma unroll
            for (int ks = 0; ks < 2; ++ks)
                aG[vv][tm][ks] = (((vv*3+tm)*2 + ks)*4 + jt) * 1024 + l * 16;

    const int key = lb & 7;
    const int aB0 = lb * 128 + ((lg ^ key) * 16);
    const int aB1 = lb * 128 + (((4 + lg) ^ key) * 16);
    const int aWr = lb * 128 + (((jt * 2 + (lg >> 1)) ^ key) * 16) + (lg & 1) * 8;

    // asm-pinned A fragments: 2 parities x (2v x 3tm x 2ks) = 24 quads
    i32x4 A_0_000, A_0_001, A_0_010, A_0_011, A_0_020, A_0_021;
    i32x4 A_0_100, A_0_101, A_0_110, A_0_111, A_0_120, A_0_121;
    i32x4 A_1_000, A_1_001, A_1_010, A_1_011, A_1_020, A_1_021;
    i32x4 A_1_100, A_1_101, A_1_110, A_1_111, A_1_120, A_1_121;

    float ls0 = 0.f, ls1 = 0.f;
    f32x4 eg0, eg1, acC0_0, acC0_1, acC1_0, acC1_1;

    PREFETCH(0, 0);                         // site-0 A fragments -> parity-0 regs

    const uint* mp = (const uint*)(ws + WMASK_OFF);
    const uint4 vmg0 = *(const uint4*)(mp + (size_t)b0 * 4);
    const uint4 vmg1 = *(const uint4*)(mp + (size_t)b1 * 4);
    // c1 mask words shifted by one site (epi of acc(s) runs at phase A of s+1)
    const uint s1a = vmg1.x << 1;
    const uint s1b = (vmg1.y << 1) | (vmg1.x >> 31);
    const uint s1c = (vmg1.z << 1) | (vmg1.y >> 31);
    const uint s1d = (vmg1.w << 1) | (vmg1.z >> 31);

    const int c00 = cfg[b0 * NSITES], c01 = cfg[b1 * NSITES];
    const int jout = jt * 16 + lg * 4;
    f32x4 ig0, ig1;
    #pragma unroll
    for (int r = 0; r < 4; ++r) {
        ig0[r] = left[c00 * BOND + jout + r];
        ig1[r] = left[c01 * BOND + jout + r];
    }
    // seed: c0 env written now; c1 env written by site-0 phase A epi (acc preset)
    acC0_0 = ig0; acC0_1 = ig0;
    acC1_0 = ig1; acC1_1 = ig1;
    eg0 = ig0; eg1 = ig1;
    EPI(eg0, acC0_0, acC0_1, 0u, false, false, RED_OFF, ls0, 0);
    asm volatile("s_waitcnt lgkmcnt(0)" ::: "memory");
    __builtin_amdgcn_s_barrier();

    RUN_CHUNK(0, vmg0.x, s1a, 32, false, true)
    RUN_CHUNK(1, vmg0.y, s1b, 32, true,  true)
    RUN_CHUNK(2, vmg0.z, s1c, 32, true,  true)
    RUN_CHUNK(3, vmg0.w, s1d, 30, true,  false)

    // pending c1 epilogue for acc(125): select only (bit 125 = word3 bit 29)
    {
        const bool v_ = ((vmg1.w >> 29) & 1u) != 0u;
        eg1.x = v_ ? acC1_1.x : acC1_0.x;  eg1.y = v_ ? acC1_1.y : acC1_0.y;
        eg1.z = v_ ? acC1_1.z : acC1_0.z;  eg1.w = v_ ? acC1_1.w : acC1_0.w;
    }

    // ---- epilogue: contract with right tensor, reduce across waves ----
    {
        const int vl0 = cfg[b0 * NSITES + 127], vl1 = cfg[b1 * NSITES + 127];
        float p0 = eg0.x * right[(jout + 0) * 2 + vl0] + eg0.y * right[(jout + 1) * 2 + vl0]
                 + eg0.z * right[(jout + 2) * 2 + vl0] + eg0.w * right[(jout + 3) * 2 + vl0];
        float p1 = eg1.x * right[(jout + 0) * 2 + vl1] + eg1.y * right[(jout + 1) * 2 + vl1]
                 + eg1.z * right[(jout + 2) * 2 + vl1] + eg1.w * right[(jout + 3) * 2 + vl1];
        p0 += __shfl_xor(p0, 16); p0 += __shfl_xor(p0, 32);
        p1 += __shfl_xor(p1, 16); p1 += __shfl_xor(p1, 32);
        if (lg == 0) {
            *(float*)(smem + RED_OFF + lb * 16 + jt * 4) = p0;
            *(float*)(smem + RED_OFF + 256 + lb * 16 + jt * 4) = p1;
        }
    }
    __syncthreads();
    if (w == 0 && l < 16) {
        f32x4 q0 = *(const f32x4*)(smem + RED_OFF + lb * 16);
        f32x4 q1 = *(const f32x4*)(smem + RED_OFF + 256 + lb * 16);
        const float s0 = (q0.x + q0.y) + (q0.z + q0.w);
        const float s1 = (q1.x + q1.y) + (q1.z + q1.w);
        out[b0] = 2.0f * (ls0 + logf(fmaxf(fabsf(s0), 1e-30f)));
        out[b1] = 2.0f * (ls1 + logf(fmaxf(fabsf(s1), 1e-30f)));
    }
}

// ================= fallback fp32 kernel (R0, known-good) =================
#define WPB     16
#define TPB     (WPB * 64)
#define SITE_ELTS (BOND * 2 * BOND)

__global__ __launch_bounds__(TPB, 2) void mps_logamp_fp32(
    const int*   __restrict__ cfg, const float* __restrict__ left,
    const float* __restrict__ bulk, const float* __restrict__ right,
    float* __restrict__ out)
{
    __shared__ float Abuf[2][SITE_ELTS];
    __shared__ float envs[WPB][BOND];
    __shared__ int   cfgs[WPB * NSITES];
    const int t = threadIdx.x;
    const int w = t >> 6, l = t & 63;
    const int bbase = blockIdx.x * WPB;
    const int b = bbase + w;
    cfgs[t] = cfg[bbase * NSITES + t];
    cfgs[t + TPB] = cfg[bbase * NSITES + t + TPB];
    { const float4* src = (const float4*)bulk; float4* dst = (float4*)(&Abuf[0][0]);
      dst[t] = src[t]; dst[t + TPB] = src[t + TPB]; }
    __syncthreads();
    const int c0 = cfgs[w * NSITES];
    float e = left[c0 * BOND + l];
    float m = fabsf(e);
    #pragma unroll
    for (int k = 32; k; k >>= 1) m = fmaxf(m, __shfl_xor(m, k));
    m = fmaxf(m, 1e-30f);
    e = e / m;
    float ls = logf(m);
    envs[w][l] = e;
    for (int s = 0; s < NBULK; ++s) {
        const int cur = s & 1, nxt = cur ^ 1;
        const bool pf = (s + 1 < NBULK);
        float4 p0, p1;
        if (pf) { const float4* src = (const float4*)(bulk + (size_t)(s + 1) * SITE_ELTS);
                  p0 = src[t]; p1 = src[t + TPB]; }
        const int v = cfgs[w * NSITES + (s + 1)];
        const float* Ap = &Abuf[cur][v * BOND + l];
        const float* ev = &envs[w][0];
        float acc = 0.0f;
        #pragma unroll
        for (int i = 0; i < BOND; i += 4) {
            const float4 e4 = *(const float4*)(ev + i);
            acc = fmaf(e4.x, Ap[(i + 0) * 128], acc);
            acc = fmaf(e4.y, Ap[(i + 1) * 128], acc);
            acc = fmaf(e4.z, Ap[(i + 2) * 128], acc);
            acc = fmaf(e4.w, Ap[(i + 3) * 128], acc);
        }
        float mm = fabsf(acc);
        #pragma unroll
        for (int k = 32; k; k >>= 1) mm = fmaxf(mm, __shfl_xor(mm, k));
        mm = fmaxf(mm, 1e-30f);
        acc = acc / mm;
        ls += logf(mm);
        if (pf) { float4* dst = (float4*)(&Abuf[nxt][0]); dst[t] = p0; dst[t + TPB] = p1; }
        envs[w][l] = acc;
        e = acc;
        __syncthreads();
    }
    const int vl = cfgs[w * NSITES + (NSITES - 1)];
    float p = e * right[l * 2 + vl];
    #pragma unroll
    for (int k = 32; k; k >>= 1) p += __shfl_xor(p, k);
    const float am = fmaxf(fabsf(p), 1e-30f);
    if (l == 0) out[b] = 2.0f * (ls + logf(am));
}

extern "C" void kernel_launch(void* const* d_in, const int* in_sizes, int n_in,
                              void* d_out, int out_size, void* d_ws, size_t ws_size,
                              hipStream_t stream) {
    const int*   cfg   = (const int*)d_in[0];
    const float* left  = (const float*)d_in[1];
    const float* bulk  = (const float*)d_in[2];
    const float* right = (const float*)d_in[3];
    float*       out   = (float*)d_out;

    if (ws_size >= WS_NEED) {
        hipLaunchKernelGGL(prep_w, dim3(NBULK), dim3(256), 0, stream,
                           bulk, (char*)d_ws);
        hipLaunchKernelGGL(prep_mask, dim3(BATCH / 2), dim3(256), 0, stream,
                           cfg, (uint*)((char*)d_ws + WMASK_OFF));
        hipLaunchKernelGGL(mps_main, dim3(BATCH / 32), dim3(256), SMEM_SZ, stream,
                           cfg, left, right, (const char*)d_ws, out);
    } else {
        hipLaunchKernelGGL(mps_logamp_fp32, dim3(BATCH / WPB), dim3(TPB), 0, stream,
                           cfg, left, bulk, right, out);
    }
}